// Round 18
// baseline (661.077 us; speedup 1.0000x reference)
//
#include <hip/hip_runtime.h>
#include <hip/hip_cooperative_groups.h>
#include <math.h>

namespace cg = cooperative_groups;

#define NF 128      // feature dim (in == out == 128)

typedef __bf16 bf16x8 __attribute__((ext_vector_type(8)));
typedef float  f32x4  __attribute__((ext_vector_type(4)));

// ---- bf16 helpers ---------------------------------------------------------

__device__ __forceinline__ unsigned short f2bf(float f) {
    unsigned int u = __float_as_uint(f);
    u = (u + 0x7fffu + ((u >> 16) & 1u)) >> 16;   // round-to-nearest-even
    return (unsigned short)u;
}
__device__ __forceinline__ float bf2f(unsigned short s) {
    return __uint_as_float((unsigned int)s << 16);
}

// ---- Cooperative build kernel: zero+cvt+cvtW | hist | scan | fill ---------
// grid = 1024 blocks x 256 threads (co-resident: tiny VGPR/LDS).
// Chunks of 1024 cnt-entries: nb = ceil(N/1024) <= 64.

__global__ __launch_bounds__(256) void build_kernel(
    const float* __restrict__ x, const float* __restrict__ W,
    const int* __restrict__ erow, const int* __restrict__ ecol,
    const float* __restrict__ evalv,
    uint* __restrict__ xb, unsigned short* __restrict__ Wt,
    int* __restrict__ cnt, int* __restrict__ bsum,
    int* __restrict__ off, int* __restrict__ pos, int2* __restrict__ epack,
    int N_, int E_, int nb, int n8)
{
    cg::grid_group grid = cg::this_grid();
    int t = threadIdx.x;
    int gtid = blockIdx.x * 256 + t;
    int G = gridDim.x * 256;

    __shared__ int sbuf[256];
    __shared__ int pre[64];

    // ---- P0: zero cnt; x -> xb (bf16); W -> Wt (bf16, transposed) ----
    for (int i = gtid; i < N_; i += G) cnt[i] = 0;
    for (int i = gtid; i < n8; i += G) {
        float4 a = ((const float4*)x)[i * 2];
        float4 b = ((const float4*)x)[i * 2 + 1];
        uint4 o;
        o.x = (uint)f2bf(a.x) | ((uint)f2bf(a.y) << 16);
        o.y = (uint)f2bf(a.z) | ((uint)f2bf(a.w) << 16);
        o.z = (uint)f2bf(b.x) | ((uint)f2bf(b.y) << 16);
        o.w = (uint)f2bf(b.z) | ((uint)f2bf(b.w) << 16);
        ((uint4*)xb)[i] = o;
    }
    for (int i = gtid; i < NF * NF; i += G) {
        int k = i >> 7, n = i & 127;
        Wt[n * NF + k] = f2bf(W[k * NF + n]);
    }
    grid.sync();

    // ---- P1: histogram of rows ----
    for (int e = gtid; e < E_; e += G) atomicAdd(&cnt[erow[e]], 1);
    grid.sync();

    // ---- P2a: per-chunk sums -> bsum ----
    for (int c = blockIdx.x; c < nb; c += gridDim.x) {
        int base_i = c * 1024 + t * 4;
        int s = 0;
#pragma unroll
        for (int j = 0; j < 4; j++) {
            int idx = base_i + j;
            s += (idx < N_) ? cnt[idx] : 0;
        }
        sbuf[t] = s;
        __syncthreads();
        for (int d = 128; d > 0; d >>= 1) {
            if (t < d) sbuf[t] += sbuf[t + d];
            __syncthreads();
        }
        if (t == 0) bsum[c] = sbuf[0];
        __syncthreads();
    }
    grid.sync();

    // ---- P2b: exclusive prefix of bsum (wave-scan) + chunk scans ----
    if (t < 64) {
        int v0 = (t < nb) ? bsum[t] : 0;
        int v = v0;
        for (int d = 1; d < 64; d <<= 1) {
            int u = __shfl_up(v, d, 64);
            if (t >= d) v += u;
        }
        pre[t] = v - v0;   // exclusive prefix
    }
    __syncthreads();
    for (int c = blockIdx.x; c < nb; c += gridDim.x) {
        int base_i = c * 1024 + t * 4;
        int v[4];
        int s = 0;
#pragma unroll
        for (int j = 0; j < 4; j++) {
            int idx = base_i + j;
            v[j] = (idx < N_) ? cnt[idx] : 0;
            s += v[j];
        }
        sbuf[t] = s;
        __syncthreads();
        for (int d = 1; d < 256; d <<= 1) {
            int add = (t >= d) ? sbuf[t - d] : 0;
            __syncthreads();
            sbuf[t] += add;
            __syncthreads();
        }
        int base = pre[c] + sbuf[t] - s;   // exclusive across chunk
#pragma unroll
        for (int j = 0; j < 4; j++) {
            int idx = base_i + j;
            if (idx < N_) {
                off[idx] = base;
                pos[idx] = base;
                base += v[j];
            }
        }
        __syncthreads();
    }
    if (blockIdx.x == 0 && t == 0) off[N_] = pre[nb - 1] + bsum[nb - 1];
    grid.sync();

    // ---- P3: fill packed (col,val) edge list in row-sorted order ----
    for (int e = gtid; e < E_; e += G) {
        int p = atomicAdd(&pos[erow[e]], 1);
        int2 pk;
        pk.x = ecol[e];
        pk.y = __float_as_int(evalv[e]);
        epack[p] = pk;
    }
}

// ---- SpMM: one wave per row; bf16 gathers, 16 lanes per edge --------------

#define UNPK_FMA(u, v, a0, a1)                         \
    a0 += (v) * __uint_as_float((u) << 16);            \
    a1 += (v) * __uint_as_float((u) & 0xffff0000u);

__global__ __launch_bounds__(256) void spmm_kernel(
    const unsigned short* __restrict__ xb, const float* __restrict__ h0,
    const int* __restrict__ off, const int2* __restrict__ epack,
    unsigned short* __restrict__ supb, const float* __restrict__ alpha_p, int N_) {
    int w = (blockIdx.x * 256 + threadIdx.x) >> 6;   // wave id == row
    if (w >= N_) return;
    int lane = threadIdx.x & 63;
    int g    = lane >> 4;      // edge-group 0..3
    int seg  = lane & 15;      // 8-feature segment
    int s = off[w], e = off[w + 1];
    float acc[8] = {};
    int i = s + g;
    for (; i + 4 < e; i += 8) {    // edges i and i+4 for this group
        int2 e0 = epack[i];
        int2 e1 = epack[i + 4];
        float v0 = __int_as_float(e0.y);
        float v1 = __int_as_float(e1.y);
        uint4 a = *(const uint4*)(xb + (size_t)e0.x * NF + seg * 8);
        uint4 b = *(const uint4*)(xb + (size_t)e1.x * NF + seg * 8);
        UNPK_FMA(a.x, v0, acc[0], acc[1]);
        UNPK_FMA(a.y, v0, acc[2], acc[3]);
        UNPK_FMA(a.z, v0, acc[4], acc[5]);
        UNPK_FMA(a.w, v0, acc[6], acc[7]);
        UNPK_FMA(b.x, v1, acc[0], acc[1]);
        UNPK_FMA(b.y, v1, acc[2], acc[3]);
        UNPK_FMA(b.z, v1, acc[4], acc[5]);
        UNPK_FMA(b.w, v1, acc[6], acc[7]);
    }
    if (i < e) {
        int2 e0 = epack[i];
        float v0 = __int_as_float(e0.y);
        uint4 a = *(const uint4*)(xb + (size_t)e0.x * NF + seg * 8);
        UNPK_FMA(a.x, v0, acc[0], acc[1]);
        UNPK_FMA(a.y, v0, acc[2], acc[3]);
        UNPK_FMA(a.z, v0, acc[4], acc[5]);
        UNPK_FMA(a.w, v0, acc[6], acc[7]);
    }
#pragma unroll
    for (int j = 0; j < 8; j++) {
        acc[j] += __shfl_xor(acc[j], 16, 64);
        acc[j] += __shfl_xor(acc[j], 32, 64);
    }
    if (g == 0) {
        float alpha = *alpha_p;
        float oma = 1.0f - alpha;
        const float* h = h0 + (size_t)w * NF + seg * 8;
        float4 ha = *(const float4*)h;
        float4 hb = *(const float4*)(h + 4);
        float o0 = oma * acc[0] + alpha * ha.x;
        float o1 = oma * acc[1] + alpha * ha.y;
        float o2 = oma * acc[2] + alpha * ha.z;
        float o3 = oma * acc[3] + alpha * ha.w;
        float o4 = oma * acc[4] + alpha * hb.x;
        float o5 = oma * acc[5] + alpha * hb.y;
        float o6 = oma * acc[6] + alpha * hb.z;
        float o7 = oma * acc[7] + alpha * hb.w;
        uint4 pk;
        pk.x = (uint)f2bf(o0) | ((uint)f2bf(o1) << 16);
        pk.y = (uint)f2bf(o2) | ((uint)f2bf(o3) << 16);
        pk.z = (uint)f2bf(o4) | ((uint)f2bf(o5) << 16);
        pk.w = (uint)f2bf(o6) | ((uint)f2bf(o7) << 16);
        *(uint4*)(supb + (size_t)w * NF + seg * 8) = pk;
    }
}

// ---- MFMA GEMM + epilogue: out = theta*(supb@W) + (1-theta)*supb + x ------
// D layout (HW-verified): col = lane&15, row = (lane>>4)*4 + reg.

__global__ __launch_bounds__(256) void gemm_mfma_kernel(
    const unsigned short* __restrict__ supb, const unsigned short* __restrict__ Wt,
    const float* __restrict__ x, float* __restrict__ out,
    const float* __restrict__ lamda_p, const int* __restrict__ l_p, int n_rows) {
    int wave = threadIdx.x >> 6;
    int lane = threadIdx.x & 63;
    int m0 = blockIdx.x * 64 + wave * 16;
    if (m0 >= n_rows) return;     // n_rows % 16 == 0: tiles never straddle

    float theta = logf((*lamda_p) / (float)(*l_p) + 1.0f);
    float omt = 1.0f - theta;

    int lr = lane & 15;   // A row-offset / B col / D col
    int kg = lane >> 4;   // k-group

    bf16x8 afr[4];
    const unsigned short* abase = supb + (size_t)(m0 + lr) * NF + kg * 8;
#pragma unroll
    for (int kt = 0; kt < 4; kt++)
        afr[kt] = *reinterpret_cast<const bf16x8*>(abase + kt * 32);

#pragma unroll
    for (int nt = 0; nt < 8; nt++) {
        int n0 = nt * 16;
        const unsigned short* bbase = Wt + (size_t)(n0 + lr) * NF + kg * 8;
        f32x4 acc = {0.f, 0.f, 0.f, 0.f};
#pragma unroll
        for (int kt = 0; kt < 4; kt++) {
            bf16x8 bfr = *reinterpret_cast<const bf16x8*>(bbase + kt * 32);
            acc = __builtin_amdgcn_mfma_f32_16x16x32_bf16(afr[kt], bfr, acc, 0, 0, 0);
        }
        int ncol = n0 + lr;
#pragma unroll
        for (int j = 0; j < 4; j++) {
            int m = m0 + kg * 4 + j;
            float sv = bf2f(supb[(size_t)m * NF + ncol]);
            float xv = x[(size_t)m * NF + ncol];
            out[(size_t)m * NF + ncol] = theta * acc[j] + omt * sv + xv;
        }
    }
}

extern "C" void kernel_launch(void* const* d_in, const int* in_sizes, int n_in,
                              void* d_out, int out_size, void* d_ws, size_t ws_size,
                              hipStream_t stream) {
    const float* x       = (const float*)d_in[0];
    const float* h0      = (const float*)d_in[1];
    const int*   erow    = (const int*)d_in[2];
    const int*   ecol    = (const int*)d_in[3];
    const float* evalv   = (const float*)d_in[4];
    const float* W       = (const float*)d_in[5];
    const float* lamda_p = (const float*)d_in[6];
    const float* alpha_p = (const float*)d_in[7];
    const int*   l_p     = (const int*)d_in[8];

    int N_ = in_sizes[0] / NF;   // 50000
    int E_ = in_sizes[2];        // 800000
    int nb = (N_ + 1023) / 1024; // 49 (must be <= 64)
    int n8 = N_ * NF / 8;        // 800000

    // workspace layout (256B-aligned slabs)
    char* ws = (char*)d_ws;
    size_t o = 0;
    auto alloc = [&](size_t bytes) { char* p = ws + o; o = (o + bytes + 255) & ~(size_t)255; return p; };
    unsigned short* supb = (unsigned short*)alloc((size_t)N_ * NF * 2);  // 12.8 MB
    unsigned short* xb   = (unsigned short*)alloc((size_t)N_ * NF * 2);  // 12.8 MB
    unsigned short* Wt   = (unsigned short*)alloc((size_t)NF * NF * 2);  // 32 KB
    int*   cnt   = (int*)  alloc((size_t)N_ * sizeof(int));
    int*   off   = (int*)  alloc((size_t)(N_ + 1) * sizeof(int));
    int*   pos   = (int*)  alloc((size_t)N_ * sizeof(int));
    int2*  epack = (int2*) alloc((size_t)E_ * sizeof(int2));
    int*   bsum  = (int*)  alloc(64 * sizeof(int));

    float* out = (float*)d_out;

    // cooperative build: zero+cvt+cvtW | hist | scan | fill  (one dispatch)
    uint* xbu = (uint*)xb;
    void* args[] = {
        (void*)&x, (void*)&W, (void*)&erow, (void*)&ecol, (void*)&evalv,
        (void*)&xbu, (void*)&Wt, (void*)&cnt, (void*)&bsum,
        (void*)&off, (void*)&pos, (void*)&epack,
        (void*)&N_, (void*)&E_, (void*)&nb, (void*)&n8
    };
    hipLaunchCooperativeKernel((void*)build_kernel, dim3(1024), dim3(256),
                               args, 0, stream);

    int blocks = (N_ * 64 + 255) / 256;   // one wave per row
    spmm_kernel<<<blocks, 256, 0, stream>>>(xb, h0, off, epack, supb, alpha_p, N_);

    gemm_mfma_kernel<<<(N_ + 63) / 64, 256, 0, stream>>>(
        supb, Wt, x, out, lamda_p, l_p, N_);
}